// Round 1
// baseline (331.803 us; speedup 1.0000x reference)
//
#include <hip/hip_runtime.h>
#include <stdint.h>
#include <math.h>

#define D_IN   1024
#define NQKV   3072
#define NHEADS 16
#define DH     64
#define BATCH  4
#define SEQ    2048
#define MTOT   (BATCH*SEQ)   // 8192

typedef __bf16    bf16x8 __attribute__((ext_vector_type(8)));
typedef _Float16  f16x8  __attribute__((ext_vector_type(8)));
typedef float     f32x4  __attribute__((ext_vector_type(4)));

typedef __attribute__((address_space(3))) unsigned short       lds_us;
typedef __attribute__((address_space(1))) const unsigned short glb_us;

__device__ __forceinline__ unsigned short f2bf(float f) {
    union { float f; uint32_t u; } c; c.f = f;
    uint32_t u = c.u;
    uint32_t r = u + 0x7fffu + ((u >> 16) & 1u);  // RNE
    return (unsigned short)(r >> 16);
}
__device__ __forceinline__ float bf2f(unsigned short b) {
    union { uint32_t u; float f; } c; c.u = ((uint32_t)b) << 16;
    return c.f;
}
__device__ __forceinline__ uint32_t pkh(float a, float b) {
    auto h = __builtin_amdgcn_cvt_pkrtz(a, b);   // __fp16 ext_vector(2)
    uint32_t u;
    __builtin_memcpy(&u, &h, 4);
    return u;
}

// ---------------- stage 0a: x fp32 -> bf16 ----------------
__global__ void k_convert_x(const float* __restrict__ x, unsigned short* __restrict__ xb) {
    int i = blockIdx.x * 256 + threadIdx.x;
    float4 v = ((const float4*)x)[i];
    ushort4 o;
    o.x = f2bf(v.x); o.y = f2bf(v.y); o.z = f2bf(v.z); o.w = f2bf(v.w);
    ((ushort4*)xb)[i] = o;
}

// ---------------- stage 0b: W fp32 [K][N] -> Wt bf16 [N][K] ----------------
__global__ void k_convert_wt(const float* __restrict__ W, unsigned short* __restrict__ Wt) {
    __shared__ float tile[32][33];
    int tx = threadIdx.x, ty = threadIdx.y;
    int n0 = blockIdx.x * 32, k0 = blockIdx.y * 32;
    #pragma unroll
    for (int i = 0; i < 4; ++i) {
        int k = k0 + ty + i*8;
        tile[ty + i*8][tx] = W[(size_t)k * NQKV + n0 + tx];
    }
    __syncthreads();
    #pragma unroll
    for (int i = 0; i < 4; ++i) {
        int n = n0 + ty + i*8;
        Wt[(size_t)n * D_IN + k0 + tx] = f2bf(tile[tx][ty + i*8]);
    }
}

// ---------------- stage 1: QKV = x @ W + b, m97-style global_load_lds GEMM ----------------
// 128x128 tile, BK=32, unpadded LDS [128][32] (2-way bank alias = free), DMA staging.
// Q columns (col%192 < 64) pre-scaled by 0.125*log2e so k_attn's exp2 needs no mul.
__global__ __launch_bounds__(256) void k_gemm_qkv(
    const unsigned short* __restrict__ A,   // [8192][1024] bf16
    const unsigned short* __restrict__ Bt,  // [3072][1024] bf16
    const float* __restrict__ bias,         // [3072]
    unsigned short* __restrict__ C)         // [8192][3072] bf16
{
    __shared__ __align__(16) unsigned short As[128*32];
    __shared__ __align__(16) unsigned short Bs[128*32];
    const int t = threadIdx.x;
    const int wave = t >> 6, lane = t & 63, quad = lane >> 4, l15 = lane & 15;
    const int wm = wave >> 1, wn = wave & 1;
    const int m0 = blockIdx.y * 128, n0 = blockIdx.x * 128;
    const int crow = lane >> 2;          // row within 16-row chunk
    const int ccol = (lane & 3) << 3;    // short col within row

    f32x4 acc[4][4] = {};
    lds_us* As3 = (lds_us*)As;
    lds_us* Bs3 = (lds_us*)Bs;

    for (int k0 = 0; k0 < D_IN; k0 += 32) {
        // stage A,B tiles: each wave DMAs 2 chunks of 16 rows each (1024 B per instr)
        #pragma unroll
        for (int j = 0; j < 2; ++j) {
            int chunk = wave*2 + j;
            const unsigned short* ga = A  + (size_t)(m0 + chunk*16 + crow)*D_IN + k0 + ccol;
            const unsigned short* gb = Bt + (size_t)(n0 + chunk*16 + crow)*D_IN + k0 + ccol;
            __builtin_amdgcn_global_load_lds((glb_us*)ga, As3 + chunk*512, 16, 0, 0);
            __builtin_amdgcn_global_load_lds((glb_us*)gb, Bs3 + chunk*512, 16, 0, 0);
        }
        __syncthreads();   // drains vmcnt -> staging visible
        bf16x8 a[4], b[4];
        #pragma unroll
        for (int tm = 0; tm < 4; ++tm)
            a[tm] = *(const bf16x8*)(&As[(wm*64 + tm*16 + l15)*32 + quad*8]);
        #pragma unroll
        for (int tn = 0; tn < 4; ++tn)
            b[tn] = *(const bf16x8*)(&Bs[(wn*64 + tn*16 + l15)*32 + quad*8]);
        #pragma unroll
        for (int tm = 0; tm < 4; ++tm)
            #pragma unroll
            for (int tn = 0; tn < 4; ++tn)
                acc[tm][tn] = __builtin_amdgcn_mfma_f32_16x16x32_bf16(a[tm], b[tn], acc[tm][tn], 0, 0, 0);
        __syncthreads();   // protect LDS before next iteration's DMA overwrite
    }
    const float qs = 0.125f * 1.44269504089f;
    #pragma unroll
    for (int tn = 0; tn < 4; ++tn) {
        int col = n0 + wn*64 + tn*16 + l15;
        float bv = bias[col];
        float s = ((col % 192) < 64) ? qs : 1.0f;   // pre-scale Q columns
        #pragma unroll
        for (int tm = 0; tm < 4; ++tm) {
            #pragma unroll
            for (int r = 0; r < 4; ++r) {
                int row = m0 + wm*64 + tm*16 + quad*4 + r;
                C[(size_t)row*NQKV + col] = f2bf((acc[tm][tn][r] + bv) * s);
            }
        }
    }
}

// ---------------- stage 1b: V (bf16, strided in qkv) -> Vt f16 [bh][d][s] ----------------
// grid swapped to (bh, s-tile) so all of one bh's V^T is written on ONE XCD's L2
// (matches k_attn's new block->XCD mapping; attn reads it warm).
#define TP 66
__global__ __launch_bounds__(256) void k_transpose_v(
    const unsigned short* __restrict__ qkv,
    unsigned short* __restrict__ vtg)       // f16 bits
{
    __shared__ unsigned short T[64*TP];     // [s][d] as f16
    const int t = threadIdx.x;
    const int bh = blockIdx.x, b = bh >> 4, h = bh & 15;
    const int s0 = blockIdx.y * 64;
    const unsigned short* src = qkv + (size_t)(b*SEQ + s0)*NQKV + h*(3*DH) + 2*DH;
    #pragma unroll
    for (int i = 0; i < 2; ++i) {
        int idx = t + i*256;
        int s = idx >> 3, c = (idx & 7) << 3;
        uint4 v = *(const uint4*)(src + (size_t)s*NQKV + c);   // 16 B = 8 bf16
        unsigned short* dst = &T[s*TP + c];
        const unsigned short* pv = (const unsigned short*)&v;
        #pragma unroll
        for (int j = 0; j < 8; ++j) {
            _Float16 hv = (_Float16)bf2f(pv[j]);
            dst[j] = *(unsigned short*)&hv;
        }
    }
    __syncthreads();
    unsigned short* out = vtg + (size_t)bh * DH * SEQ + s0;
    #pragma unroll
    for (int i = 0; i < 16; ++i) {
        int idx = t + i*256;
        int d = idx >> 6, s = idx & 63;
        out[(size_t)d * SEQ + s] = T[s*TP + d];
    }
}

// ---------------- stage 2: transposed flash attention, barrier-free K-loop ----------------
// R1 changes vs 297us baseline:
//  * kf/vf SINGLE-buffered with early-issue prefetch into the SAME registers.
//    K is consumed at iter start, V at iter end, so the reload issued right after
//    the last use has a full phase (~300-500cy) of QK/exp/PV work to hide under.
//    Saves 32 VGPRs: combined arch+acc was ~188 (124 arch + 64 AGPR) -> 2 waves/SIMD
//    (the REAL cause of the measured 20% occupancy); now ~156 -> 3 waves/SIMD.
//  * __launch_bounds__(256,3): cap combined regs at 168 to lock in 3 waves/EU.
//    (256,4) is known-bad (R6: cap 128 -> 2GB scratch); working set ~156 fits 168.
//  * grid swapped to (bh, qtile): linear id = bh + 64*qtile => all 32 blocks sharing
//    one bh's 512KB K/V land on the SAME XCD -> kills the 8x L2 replication that
//    showed as 139MB FETCH (ideal ~64MB).
//  * s_setprio(1) around MFMA clusters (T5, attn-proven +4-7%).
//  * PV reads pb per-tq (not all 4 up front) to keep PV-phase reg peak under the cap.
#define PPAD 40   // P^T row pitch (shorts)
#define OPAD 72   // O^T stash row pitch (shorts)
__global__ __launch_bounds__(256, 3) void k_attn(
    const unsigned short* __restrict__ qkv, // bf16 (Q pre-scaled by 0.125*log2e)
    const unsigned short* __restrict__ vtg, // f16 V^T [bh][d][s]
    float* __restrict__ out)
{
    __shared__ __align__(16) unsigned short PO[4*64*OPAD];  // 36 KB union: Pl (loop) / Os (epilogue)
    __shared__ float Lp[4*64];

    const int t = threadIdx.x;
    const int wave = t >> 6, lane = t & 63, quad = lane >> 4, l15 = lane & 15;
    const int bh = blockIdx.x, b = bh >> 4, h = bh & 15;
    const int m0 = blockIdx.y * 64;
    const unsigned short* base  = qkv + (size_t)(b*SEQ)*NQKV + h*(3*DH);
    const unsigned short* kbase = base + DH;
    const unsigned short* vbase = vtg + (size_t)bh * DH * SEQ;

    // Q B-frags: B[k=d][n=q], n=l15, k=quad*8+j (+kc*32). All 64 q-rows per wave.
    bf16x8 qb[4][2];
    #pragma unroll
    for (int tq = 0; tq < 4; ++tq) {
        const unsigned short* qrow = base + (size_t)(m0 + tq*16 + l15) * NQKV;
        qb[tq][0] = *(const bf16x8*)(qrow + quad*8);
        qb[tq][1] = *(const bf16x8*)(qrow + 32 + quad*8);
    }

    f32x4 o[4][4] = {};            // O^T tiles [td][tq]: row=d, col=q
    float lp[4] = {0.f, 0.f, 0.f, 0.f};
    unsigned short* pw = &PO[wave*64*PPAD];

    // single-buffered K/V fragments (direct global loads, L2-resident on this XCD)
    bf16x8 kf[2][2];   // [tk][kc]
    f16x8  vf[4];      // [td]
    {
        int key0 = wave*32;
        #pragma unroll
        for (int tk = 0; tk < 2; ++tk) {
            const unsigned short* kr = kbase + (size_t)(key0 + tk*16 + l15)*NQKV;
            kf[tk][0] = *(const bf16x8*)(kr + quad*8);
            kf[tk][1] = *(const bf16x8*)(kr + 32 + quad*8);
        }
        #pragma unroll
        for (int td = 0; td < 4; ++td)
            vf[td] = *(const f16x8*)(vbase + (size_t)(td*16 + l15)*SEQ + key0 + quad*8);
    }

    for (int it = 0; it < 16; ++it) {
        // S^T tiles: C'[key][q]: row=key_local=tk*16+quad*4+r, col=q=tq*16+l15
        #pragma unroll
        for (int tk = 0; tk < 2; ++tk) {
            #pragma unroll
            for (int tq = 0; tq < 4; ++tq) {
                f32x4 a = {};
                __builtin_amdgcn_s_setprio(1);
                a = __builtin_amdgcn_mfma_f32_16x16x32_bf16(kf[tk][0], qb[tq][0], a, 0, 0, 0);
                a = __builtin_amdgcn_mfma_f32_16x16x32_bf16(kf[tk][1], qb[tq][1], a, 0, 0, 0);
                __builtin_amdgcn_s_setprio(0);
                float p0 = exp2f(a[0]), p1 = exp2f(a[1]);   // scale pre-folded into Q
                float p2 = exp2f(a[2]), p3 = exp2f(a[3]);
                lp[tq] += (p0 + p1) + (p2 + p3);
                uint2 u; u.x = pkh(p0, p1); u.y = pkh(p2, p3);
                *(uint2*)(&pw[(tq*16 + l15)*PPAD + tk*16 + quad*4]) = u;
            }
            // kf[tk] fully consumed -> reload same regs with next 32-key slice
            if (it < 15) {
                int key0 = (it+1)*128 + wave*32;
                const unsigned short* kr = kbase + (size_t)(key0 + tk*16 + l15)*NQKV;
                kf[tk][0] = *(const bf16x8*)(kr + quad*8);
                kf[tk][1] = *(const bf16x8*)(kr + 32 + quad*8);
            }
        }
        // O^T += V^T · P^T  (A=V^T m=d; B=P^T n=q, k=key=quad*8+j)
        #pragma unroll
        for (int tq = 0; tq < 4; ++tq) {
            f16x8 pb = *(const f16x8*)(&pw[(tq*16 + l15)*PPAD + quad*8]);
            __builtin_amdgcn_s_setprio(1);
            #pragma unroll
            for (int td = 0; td < 4; ++td)
                o[td][tq] = __builtin_amdgcn_mfma_f32_16x16x32_f16(vf[td], pb, o[td][tq], 0, 0, 0);
            __builtin_amdgcn_s_setprio(0);
        }
        // vf fully consumed -> reload same regs; a whole QK phase hides the latency
        if (it < 15) {
            int key0 = (it+1)*128 + wave*32;
            #pragma unroll
            for (int td = 0; td < 4; ++td)
                vf[td] = *(const f16x8*)(vbase + (size_t)(td*16 + l15)*SEQ + key0 + quad*8);
        }
    }

    // l partials (Lp is a separate region — safe before the union barrier)
    #pragma unroll
    for (int tq = 0; tq < 4; ++tq) {
        float s = lp[tq];
        s += __shfl_xor(s, 16);
        s += __shfl_xor(s, 32);
        if (quad == 0) Lp[wave*64 + tq*16 + l15] = s;
    }
    __syncthreads();   // all waves done reading their Pl region before Os overwrites it
    {
        unsigned short* ow = &PO[wave*64*OPAD];
        #pragma unroll
        for (int td = 0; td < 4; ++td)
            #pragma unroll
            for (int tq = 0; tq < 4; ++tq) {
                uint2 u; u.x = pkh(o[td][tq][0], o[td][tq][1]); u.y = pkh(o[td][tq][2], o[td][tq][3]);
                *(uint2*)(&ow[(tq*16 + l15)*OPAD + td*16 + quad*4]) = u;
            }
    }
    __syncthreads();
    float* outb = out + (size_t)(b*SEQ + m0) * (NHEADS*DH) + h*DH;
    #pragma unroll
    for (int i = 0; i < 16; ++i) {
        int idx = t + i*256;
        int q = idx >> 6, d = idx & 63;
        float lt = Lp[q] + Lp[64 + q] + Lp[128 + q] + Lp[192 + q];
        float s = 0.f;
        #pragma unroll
        for (int w2 = 0; w2 < 4; ++w2) {
            _Float16 hv = *(const _Float16*)&PO[(w2*64 + q)*OPAD + d];
            s += (float)hv;
        }
        outb[(size_t)q * (NHEADS*DH) + d] = s / lt;
    }
}

extern "C" void kernel_launch(void* const* d_in, const int* in_sizes, int n_in,
                              void* d_out, int out_size, void* d_ws, size_t ws_size,
                              hipStream_t stream) {
    const float* x    = (const float*)d_in[0];
    const float* W    = (const float*)d_in[1];
    const float* bias = (const float*)d_in[2];
    float* out = (float*)d_out;

    unsigned short* xb  = (unsigned short*)d_ws;                 // 16 MB (reused as vtg after GEMM)
    unsigned short* Wt  = xb  + (size_t)MTOT * D_IN;             // 6 MB
    unsigned short* qkv = Wt  + (size_t)NQKV * D_IN;             // 48 MB
    unsigned short* vtg = xb;                                    // alias: xb dead after GEMM

    hipLaunchKernelGGL(k_convert_x,   dim3(MTOT*D_IN/4/256), dim3(256),    0, stream, x, xb);
    hipLaunchKernelGGL(k_convert_wt,  dim3(NQKV/32, D_IN/32), dim3(32, 8), 0, stream, W, Wt);
    hipLaunchKernelGGL(k_gemm_qkv,    dim3(NQKV/128, MTOT/128), dim3(256), 0, stream, xb, Wt, bias, qkv);
    hipLaunchKernelGGL(k_transpose_v, dim3(BATCH*NHEADS, SEQ/64), dim3(256), 0, stream, qkv, vtg);
    hipLaunchKernelGGL(k_attn,        dim3(BATCH*NHEADS, SEQ/64), dim3(256), 0, stream, qkv, vtg, out);
}

// Round 2
// 292.713 us; speedup vs baseline: 1.1335x; 1.1335x over previous
//
#include <hip/hip_runtime.h>
#include <stdint.h>
#include <math.h>

#define D_IN   1024
#define NQKV   3072
#define NHEADS 16
#define DH     64
#define BATCH  4
#define SEQ    2048
#define MTOT   (BATCH*SEQ)   // 8192

typedef __bf16    bf16x8 __attribute__((ext_vector_type(8)));
typedef _Float16  f16x8  __attribute__((ext_vector_type(8)));
typedef float     f32x4  __attribute__((ext_vector_type(4)));

typedef __attribute__((address_space(3))) unsigned short       lds_us;
typedef __attribute__((address_space(1))) const unsigned short glb_us;

__device__ __forceinline__ unsigned short f2bf(float f) {
    union { float f; uint32_t u; } c; c.f = f;
    uint32_t u = c.u;
    uint32_t r = u + 0x7fffu + ((u >> 16) & 1u);  // RNE
    return (unsigned short)(r >> 16);
}
__device__ __forceinline__ float bf2f(unsigned short b) {
    union { uint32_t u; float f; } c; c.u = ((uint32_t)b) << 16;
    return c.f;
}
__device__ __forceinline__ uint32_t pkh(float a, float b) {
    auto h = __builtin_amdgcn_cvt_pkrtz(a, b);   // __fp16 ext_vector(2)
    uint32_t u;
    __builtin_memcpy(&u, &h, 4);
    return u;
}

// ---------------- stage 0a: x fp32 -> bf16 ----------------
__global__ void k_convert_x(const float* __restrict__ x, unsigned short* __restrict__ xb) {
    int i = blockIdx.x * 256 + threadIdx.x;
    float4 v = ((const float4*)x)[i];
    ushort4 o;
    o.x = f2bf(v.x); o.y = f2bf(v.y); o.z = f2bf(v.z); o.w = f2bf(v.w);
    ((ushort4*)xb)[i] = o;
}

// ---------------- stage 0b: W fp32 [K][N] -> Wt bf16 [N][K] ----------------
__global__ void k_convert_wt(const float* __restrict__ W, unsigned short* __restrict__ Wt) {
    __shared__ float tile[32][33];
    int tx = threadIdx.x, ty = threadIdx.y;
    int n0 = blockIdx.x * 32, k0 = blockIdx.y * 32;
    #pragma unroll
    for (int i = 0; i < 4; ++i) {
        int k = k0 + ty + i*8;
        tile[ty + i*8][tx] = W[(size_t)k * NQKV + n0 + tx];
    }
    __syncthreads();
    #pragma unroll
    for (int i = 0; i < 4; ++i) {
        int n = n0 + ty + i*8;
        Wt[(size_t)n * D_IN + k0 + tx] = f2bf(tile[tx][ty + i*8]);
    }
}

// ---------------- stage 1: QKV = x @ W + b, m97-style global_load_lds GEMM ----------------
// 128x128 tile, BK=32, unpadded LDS [128][32] (2-way bank alias = free), DMA staging.
// Q columns (col%192 < 64) pre-scaled by 0.125*log2e so k_attn's exp2 needs no mul.
__global__ __launch_bounds__(256) void k_gemm_qkv(
    const unsigned short* __restrict__ A,   // [8192][1024] bf16
    const unsigned short* __restrict__ Bt,  // [3072][1024] bf16
    const float* __restrict__ bias,         // [3072]
    unsigned short* __restrict__ C)         // [8192][3072] bf16
{
    __shared__ __align__(16) unsigned short As[128*32];
    __shared__ __align__(16) unsigned short Bs[128*32];
    const int t = threadIdx.x;
    const int wave = t >> 6, lane = t & 63, quad = lane >> 4, l15 = lane & 15;
    const int wm = wave >> 1, wn = wave & 1;
    const int m0 = blockIdx.y * 128, n0 = blockIdx.x * 128;
    const int crow = lane >> 2;          // row within 16-row chunk
    const int ccol = (lane & 3) << 3;    // short col within row

    f32x4 acc[4][4] = {};
    lds_us* As3 = (lds_us*)As;
    lds_us* Bs3 = (lds_us*)Bs;

    for (int k0 = 0; k0 < D_IN; k0 += 32) {
        // stage A,B tiles: each wave DMAs 2 chunks of 16 rows each (1024 B per instr)
        #pragma unroll
        for (int j = 0; j < 2; ++j) {
            int chunk = wave*2 + j;
            const unsigned short* ga = A  + (size_t)(m0 + chunk*16 + crow)*D_IN + k0 + ccol;
            const unsigned short* gb = Bt + (size_t)(n0 + chunk*16 + crow)*D_IN + k0 + ccol;
            __builtin_amdgcn_global_load_lds((glb_us*)ga, As3 + chunk*512, 16, 0, 0);
            __builtin_amdgcn_global_load_lds((glb_us*)gb, Bs3 + chunk*512, 16, 0, 0);
        }
        __syncthreads();   // drains vmcnt -> staging visible
        bf16x8 a[4], b[4];
        #pragma unroll
        for (int tm = 0; tm < 4; ++tm)
            a[tm] = *(const bf16x8*)(&As[(wm*64 + tm*16 + l15)*32 + quad*8]);
        #pragma unroll
        for (int tn = 0; tn < 4; ++tn)
            b[tn] = *(const bf16x8*)(&Bs[(wn*64 + tn*16 + l15)*32 + quad*8]);
        #pragma unroll
        for (int tm = 0; tm < 4; ++tm)
            #pragma unroll
            for (int tn = 0; tn < 4; ++tn)
                acc[tm][tn] = __builtin_amdgcn_mfma_f32_16x16x32_bf16(a[tm], b[tn], acc[tm][tn], 0, 0, 0);
        __syncthreads();   // protect LDS before next iteration's DMA overwrite
    }
    const float qs = 0.125f * 1.44269504089f;
    #pragma unroll
    for (int tn = 0; tn < 4; ++tn) {
        int col = n0 + wn*64 + tn*16 + l15;
        float bv = bias[col];
        float s = ((col % 192) < 64) ? qs : 1.0f;   // pre-scale Q columns
        #pragma unroll
        for (int tm = 0; tm < 4; ++tm) {
            #pragma unroll
            for (int r = 0; r < 4; ++r) {
                int row = m0 + wm*64 + tm*16 + quad*4 + r;
                C[(size_t)row*NQKV + col] = f2bf((acc[tm][tn][r] + bv) * s);
            }
        }
    }
}

// ---------------- stage 1b: V (bf16, strided in qkv) -> Vt f16 [bh][d][s] ----------------
// grid (bh, s-tile): all of one bh's V^T written on ONE XCD's L2 (matches k_attn's mapping).
#define TP 66
__global__ __launch_bounds__(256) void k_transpose_v(
    const unsigned short* __restrict__ qkv,
    unsigned short* __restrict__ vtg)       // f16 bits
{
    __shared__ unsigned short T[64*TP];     // [s][d] as f16
    const int t = threadIdx.x;
    const int bh = blockIdx.x, b = bh >> 4, h = bh & 15;
    const int s0 = blockIdx.y * 64;
    const unsigned short* src = qkv + (size_t)(b*SEQ + s0)*NQKV + h*(3*DH) + 2*DH;
    #pragma unroll
    for (int i = 0; i < 2; ++i) {
        int idx = t + i*256;
        int s = idx >> 3, c = (idx & 7) << 3;
        uint4 v = *(const uint4*)(src + (size_t)s*NQKV + c);   // 16 B = 8 bf16
        unsigned short* dst = &T[s*TP + c];
        const unsigned short* pv = (const unsigned short*)&v;
        #pragma unroll
        for (int j = 0; j < 8; ++j) {
            _Float16 hv = (_Float16)bf2f(pv[j]);
            dst[j] = *(unsigned short*)&hv;
        }
    }
    __syncthreads();
    unsigned short* out = vtg + (size_t)bh * DH * SEQ + s0;
    #pragma unroll
    for (int i = 0; i < 16; ++i) {
        int idx = t + i*256;
        int d = idx >> 6, s = idx & 63;
        out[(size_t)d * SEQ + s] = T[s*TP + d];
    }
}

// ---------------- stage 2: transposed flash attention, barrier-free K-loop ----------------
// R2: revert launch_bounds (256,3)->(256,2). R1 post-mortem: the 168-reg cap made the
// compiler spill ~20 dwords/thread (WRITE_SIZE 32->76MB scratch, dur 157->190us) even
// though occupancy hit 3 waves/SIMD. With single-buffered kf/vf the natural allocation
// is ~156 combined (92 arch + 64 acc) -> 3 waves/SIMD WITHOUT a cap, zero spill.
// Kept from R1 (both verified good):
//  * single-buffered K/V frags, reload same regs right after last use (load-to-use
//    distance = one full QK or PV phase, ~300-500cy of MFMA+exp to hide L2 latency)
//  * grid (bh, qtile): same-bh blocks land on one XCD -> K/V not replicated across
//    L2s (FETCH showed 139->88MB even WITH 42MB of spill re-reads polluting it)
//  * s_setprio(1) around MFMA clusters (T5)
#define PPAD 40   // P^T row pitch (shorts)
#define OPAD 72   // O^T stash row pitch (shorts)
__global__ __launch_bounds__(256, 2) void k_attn(
    const unsigned short* __restrict__ qkv, // bf16 (Q pre-scaled by 0.125*log2e)
    const unsigned short* __restrict__ vtg, // f16 V^T [bh][d][s]
    float* __restrict__ out)
{
    __shared__ __align__(16) unsigned short PO[4*64*OPAD];  // 36 KB union: Pl (loop) / Os (epilogue)
    __shared__ float Lp[4*64];

    const int t = threadIdx.x;
    const int wave = t >> 6, lane = t & 63, quad = lane >> 4, l15 = lane & 15;
    const int bh = blockIdx.x, b = bh >> 4, h = bh & 15;
    const int m0 = blockIdx.y * 64;
    const unsigned short* base  = qkv + (size_t)(b*SEQ)*NQKV + h*(3*DH);
    const unsigned short* kbase = base + DH;
    const unsigned short* vbase = vtg + (size_t)bh * DH * SEQ;

    // Q B-frags: B[k=d][n=q], n=l15, k=quad*8+j (+kc*32). All 64 q-rows per wave.
    bf16x8 qb[4][2];
    #pragma unroll
    for (int tq = 0; tq < 4; ++tq) {
        const unsigned short* qrow = base + (size_t)(m0 + tq*16 + l15) * NQKV;
        qb[tq][0] = *(const bf16x8*)(qrow + quad*8);
        qb[tq][1] = *(const bf16x8*)(qrow + 32 + quad*8);
    }

    f32x4 o[4][4] = {};            // O^T tiles [td][tq]: row=d, col=q
    float lp[4] = {0.f, 0.f, 0.f, 0.f};
    unsigned short* pw = &PO[wave*64*PPAD];

    // single-buffered K/V fragments (direct global loads, L2-resident on this XCD)
    bf16x8 kf[2][2];   // [tk][kc]
    f16x8  vf[4];      // [td]
    {
        int key0 = wave*32;
        #pragma unroll
        for (int tk = 0; tk < 2; ++tk) {
            const unsigned short* kr = kbase + (size_t)(key0 + tk*16 + l15)*NQKV;
            kf[tk][0] = *(const bf16x8*)(kr + quad*8);
            kf[tk][1] = *(const bf16x8*)(kr + 32 + quad*8);
        }
        #pragma unroll
        for (int td = 0; td < 4; ++td)
            vf[td] = *(const f16x8*)(vbase + (size_t)(td*16 + l15)*SEQ + key0 + quad*8);
    }

    for (int it = 0; it < 16; ++it) {
        // S^T tiles: C'[key][q]: row=key_local=tk*16+quad*4+r, col=q=tq*16+l15
        #pragma unroll
        for (int tk = 0; tk < 2; ++tk) {
            #pragma unroll
            for (int tq = 0; tq < 4; ++tq) {
                f32x4 a = {};
                __builtin_amdgcn_s_setprio(1);
                a = __builtin_amdgcn_mfma_f32_16x16x32_bf16(kf[tk][0], qb[tq][0], a, 0, 0, 0);
                a = __builtin_amdgcn_mfma_f32_16x16x32_bf16(kf[tk][1], qb[tq][1], a, 0, 0, 0);
                __builtin_amdgcn_s_setprio(0);
                float p0 = exp2f(a[0]), p1 = exp2f(a[1]);   // scale pre-folded into Q
                float p2 = exp2f(a[2]), p3 = exp2f(a[3]);
                lp[tq] += (p0 + p1) + (p2 + p3);
                uint2 u; u.x = pkh(p0, p1); u.y = pkh(p2, p3);
                *(uint2*)(&pw[(tq*16 + l15)*PPAD + tk*16 + quad*4]) = u;
            }
            // kf[tk] fully consumed -> reload same regs with next 32-key slice
            if (it < 15) {
                int key0 = (it+1)*128 + wave*32;
                const unsigned short* kr = kbase + (size_t)(key0 + tk*16 + l15)*NQKV;
                kf[tk][0] = *(const bf16x8*)(kr + quad*8);
                kf[tk][1] = *(const bf16x8*)(kr + 32 + quad*8);
            }
        }
        // O^T += V^T · P^T  (A=V^T m=d; B=P^T n=q, k=key=quad*8+j)
        #pragma unroll
        for (int tq = 0; tq < 4; ++tq) {
            f16x8 pb = *(const f16x8*)(&pw[(tq*16 + l15)*PPAD + quad*8]);
            __builtin_amdgcn_s_setprio(1);
            #pragma unroll
            for (int td = 0; td < 4; ++td)
                o[td][tq] = __builtin_amdgcn_mfma_f32_16x16x32_f16(vf[td], pb, o[td][tq], 0, 0, 0);
            __builtin_amdgcn_s_setprio(0);
        }
        // vf fully consumed -> reload same regs; a whole QK phase hides the latency
        if (it < 15) {
            int key0 = (it+1)*128 + wave*32;
            #pragma unroll
            for (int td = 0; td < 4; ++td)
                vf[td] = *(const f16x8*)(vbase + (size_t)(td*16 + l15)*SEQ + key0 + quad*8);
        }
    }

    // l partials (Lp is a separate region — safe before the union barrier)
    #pragma unroll
    for (int tq = 0; tq < 4; ++tq) {
        float s = lp[tq];
        s += __shfl_xor(s, 16);
        s += __shfl_xor(s, 32);
        if (quad == 0) Lp[wave*64 + tq*16 + l15] = s;
    }
    __syncthreads();   // all waves done reading their Pl region before Os overwrites it
    {
        unsigned short* ow = &PO[wave*64*OPAD];
        #pragma unroll
        for (int td = 0; td < 4; ++td)
            #pragma unroll
            for (int tq = 0; tq < 4; ++tq) {
                uint2 u; u.x = pkh(o[td][tq][0], o[td][tq][1]); u.y = pkh(o[td][tq][2], o[td][tq][3]);
                *(uint2*)(&ow[(tq*16 + l15)*OPAD + td*16 + quad*4]) = u;
            }
    }
    __syncthreads();
    float* outb = out + (size_t)(b*SEQ + m0) * (NHEADS*DH) + h*DH;
    #pragma unroll
    for (int i = 0; i < 16; ++i) {
        int idx = t + i*256;
        int q = idx >> 6, d = idx & 63;
        float lt = Lp[q] + Lp[64 + q] + Lp[128 + q] + Lp[192 + q];
        float s = 0.f;
        #pragma unroll
        for (int w2 = 0; w2 < 4; ++w2) {
            _Float16 hv = *(const _Float16*)&PO[(w2*64 + q)*OPAD + d];
            s += (float)hv;
        }
        outb[(size_t)q * (NHEADS*DH) + d] = s / lt;
    }
}

extern "C" void kernel_launch(void* const* d_in, const int* in_sizes, int n_in,
                              void* d_out, int out_size, void* d_ws, size_t ws_size,
                              hipStream_t stream) {
    const float* x    = (const float*)d_in[0];
    const float* W    = (const float*)d_in[1];
    const float* bias = (const float*)d_in[2];
    float* out = (float*)d_out;

    unsigned short* xb  = (unsigned short*)d_ws;                 // 16 MB (reused as vtg after GEMM)
    unsigned short* Wt  = xb  + (size_t)MTOT * D_IN;             // 6 MB
    unsigned short* qkv = Wt  + (size_t)NQKV * D_IN;             // 48 MB
    unsigned short* vtg = xb;                                    // alias: xb dead after GEMM

    hipLaunchKernelGGL(k_convert_x,   dim3(MTOT*D_IN/4/256), dim3(256),    0, stream, x, xb);
    hipLaunchKernelGGL(k_convert_wt,  dim3(NQKV/32, D_IN/32), dim3(32, 8), 0, stream, W, Wt);
    hipLaunchKernelGGL(k_gemm_qkv,    dim3(NQKV/128, MTOT/128), dim3(256), 0, stream, xb, Wt, bias, qkv);
    hipLaunchKernelGGL(k_transpose_v, dim3(BATCH*NHEADS, SEQ/64), dim3(256), 0, stream, qkv, vtg);
    hipLaunchKernelGGL(k_attn,        dim3(BATCH*NHEADS, SEQ/64), dim3(256), 0, stream, qkv, vtg, out);
}

// Round 3
// 290.349 us; speedup vs baseline: 1.1428x; 1.0081x over previous
//
#include <hip/hip_runtime.h>
#include <stdint.h>
#include <math.h>

#define D_IN   1024
#define NQKV   3072
#define NHEADS 16
#define DH     64
#define BATCH  4
#define SEQ    2048
#define MTOT   (BATCH*SEQ)   // 8192

typedef __bf16    bf16x8 __attribute__((ext_vector_type(8)));
typedef _Float16  f16x8  __attribute__((ext_vector_type(8)));
typedef float     f32x4  __attribute__((ext_vector_type(4)));

typedef __attribute__((address_space(3))) unsigned short       lds_us;
typedef __attribute__((address_space(1))) const unsigned short glb_us;

__device__ __forceinline__ unsigned short f2bf(float f) {
    union { float f; uint32_t u; } c; c.f = f;
    uint32_t u = c.u;
    uint32_t r = u + 0x7fffu + ((u >> 16) & 1u);  // RNE
    return (unsigned short)(r >> 16);
}
__device__ __forceinline__ float bf2f(unsigned short b) {
    union { uint32_t u; float f; } c; c.u = ((uint32_t)b) << 16;
    return c.f;
}
__device__ __forceinline__ uint32_t pkh(float a, float b) {
    auto h = __builtin_amdgcn_cvt_pkrtz(a, b);   // __fp16 ext_vector(2)
    uint32_t u;
    __builtin_memcpy(&u, &h, 4);
    return u;
}

// ---------------- stage 0a: x fp32 -> bf16 ----------------
__global__ void k_convert_x(const float* __restrict__ x, unsigned short* __restrict__ xb) {
    int i = blockIdx.x * 256 + threadIdx.x;
    float4 v = ((const float4*)x)[i];
    ushort4 o;
    o.x = f2bf(v.x); o.y = f2bf(v.y); o.z = f2bf(v.z); o.w = f2bf(v.w);
    ((ushort4*)xb)[i] = o;
}

// ---------------- stage 0b: W fp32 [K][N] -> Wt bf16 [N][K] ----------------
__global__ void k_convert_wt(const float* __restrict__ W, unsigned short* __restrict__ Wt) {
    __shared__ float tile[32][33];
    int tx = threadIdx.x, ty = threadIdx.y;
    int n0 = blockIdx.x * 32, k0 = blockIdx.y * 32;
    #pragma unroll
    for (int i = 0; i < 4; ++i) {
        int k = k0 + ty + i*8;
        tile[ty + i*8][tx] = W[(size_t)k * NQKV + n0 + tx];
    }
    __syncthreads();
    #pragma unroll
    for (int i = 0; i < 4; ++i) {
        int n = n0 + ty + i*8;
        Wt[(size_t)n * D_IN + k0 + tx] = f2bf(tile[tx][ty + i*8]);
    }
}

// ---------------- stage 1: QKV = x @ W + b, m97-style global_load_lds GEMM ----------------
// 128x128 tile, BK=32, unpadded LDS [128][32] (2-way bank alias = free), DMA staging.
// Q columns (col%192 < 64) pre-scaled by 0.125*log2e so k_attn's exp2 needs no mul.
__global__ __launch_bounds__(256) void k_gemm_qkv(
    const unsigned short* __restrict__ A,   // [8192][1024] bf16
    const unsigned short* __restrict__ Bt,  // [3072][1024] bf16
    const float* __restrict__ bias,         // [3072]
    unsigned short* __restrict__ C)         // [8192][3072] bf16
{
    __shared__ __align__(16) unsigned short As[128*32];
    __shared__ __align__(16) unsigned short Bs[128*32];
    const int t = threadIdx.x;
    const int wave = t >> 6, lane = t & 63, quad = lane >> 4, l15 = lane & 15;
    const int wm = wave >> 1, wn = wave & 1;
    const int m0 = blockIdx.y * 128, n0 = blockIdx.x * 128;
    const int crow = lane >> 2;          // row within 16-row chunk
    const int ccol = (lane & 3) << 3;    // short col within row

    f32x4 acc[4][4] = {};
    lds_us* As3 = (lds_us*)As;
    lds_us* Bs3 = (lds_us*)Bs;

    for (int k0 = 0; k0 < D_IN; k0 += 32) {
        // stage A,B tiles: each wave DMAs 2 chunks of 16 rows each (1024 B per instr)
        #pragma unroll
        for (int j = 0; j < 2; ++j) {
            int chunk = wave*2 + j;
            const unsigned short* ga = A  + (size_t)(m0 + chunk*16 + crow)*D_IN + k0 + ccol;
            const unsigned short* gb = Bt + (size_t)(n0 + chunk*16 + crow)*D_IN + k0 + ccol;
            __builtin_amdgcn_global_load_lds((glb_us*)ga, As3 + chunk*512, 16, 0, 0);
            __builtin_amdgcn_global_load_lds((glb_us*)gb, Bs3 + chunk*512, 16, 0, 0);
        }
        __syncthreads();   // drains vmcnt -> staging visible
        bf16x8 a[4], b[4];
        #pragma unroll
        for (int tm = 0; tm < 4; ++tm)
            a[tm] = *(const bf16x8*)(&As[(wm*64 + tm*16 + l15)*32 + quad*8]);
        #pragma unroll
        for (int tn = 0; tn < 4; ++tn)
            b[tn] = *(const bf16x8*)(&Bs[(wn*64 + tn*16 + l15)*32 + quad*8]);
        #pragma unroll
        for (int tm = 0; tm < 4; ++tm)
            #pragma unroll
            for (int tn = 0; tn < 4; ++tn)
                acc[tm][tn] = __builtin_amdgcn_mfma_f32_16x16x32_bf16(a[tm], b[tn], acc[tm][tn], 0, 0, 0);
        __syncthreads();   // protect LDS before next iteration's DMA overwrite
    }
    const float qs = 0.125f * 1.44269504089f;
    #pragma unroll
    for (int tn = 0; tn < 4; ++tn) {
        int col = n0 + wn*64 + tn*16 + l15;
        float bv = bias[col];
        float s = ((col % 192) < 64) ? qs : 1.0f;   // pre-scale Q columns
        #pragma unroll
        for (int tm = 0; tm < 4; ++tm) {
            #pragma unroll
            for (int r = 0; r < 4; ++r) {
                int row = m0 + wm*64 + tm*16 + quad*4 + r;
                C[(size_t)row*NQKV + col] = f2bf((acc[tm][tn][r] + bv) * s);
            }
        }
    }
}

// ---------------- stage 1b: V (bf16, strided in qkv) -> Vt f16 [bh][d][s] ----------------
// grid (bh, s-tile): all of one bh's V^T written on ONE XCD's L2 (matches k_attn's mapping).
#define TP 66
__global__ __launch_bounds__(256) void k_transpose_v(
    const unsigned short* __restrict__ qkv,
    unsigned short* __restrict__ vtg)       // f16 bits
{
    __shared__ unsigned short T[64*TP];     // [s][d] as f16
    const int t = threadIdx.x;
    const int bh = blockIdx.x, b = bh >> 4, h = bh & 15;
    const int s0 = blockIdx.y * 64;
    const unsigned short* src = qkv + (size_t)(b*SEQ + s0)*NQKV + h*(3*DH) + 2*DH;
    #pragma unroll
    for (int i = 0; i < 2; ++i) {
        int idx = t + i*256;
        int s = idx >> 3, c = (idx & 7) << 3;
        uint4 v = *(const uint4*)(src + (size_t)s*NQKV + c);   // 16 B = 8 bf16
        unsigned short* dst = &T[s*TP + c];
        const unsigned short* pv = (const unsigned short*)&v;
        #pragma unroll
        for (int j = 0; j < 8; ++j) {
            _Float16 hv = (_Float16)bf2f(pv[j]);
            dst[j] = *(unsigned short*)&hv;
        }
    }
    __syncthreads();
    unsigned short* out = vtg + (size_t)bh * DH * SEQ + s0;
    #pragma unroll
    for (int i = 0; i < 16; ++i) {
        int idx = t + i*256;
        int d = idx >> 6, s = idx & 63;
        out[(size_t)d * SEQ + s] = T[s*TP + d];
    }
}

// ---------------- stage 2: transposed flash attention, barrier-free K-loop ----------------
// R3: Q fragments moved from registers to LDS. Rationale: qb[4][2] (32 VGPRs) was
// IDENTICAL across all 4 waves (same 64 q-rows per block). R2 landed at 92 arch +
// 64 AGPR = 156 combined > 128 -> still 2 waves/SIMD (occupancy stuck at 21%; HW
// granularity steps at 64/128/256). Dropping qb targets ~64 arch + 64 acc = 128
// -> 4 waves/SIMD, zero spill, no forced cap (R1 lesson).
//  * Q tile lives in the DEAD TAIL of the PO union during the loop: Pl uses only
//    4*64*PPAD = 20KB of the 36KB buffer; Q (64 rows x 72-padded = 9KB) fits after.
//    LDS stays 37888 B -> 4 blocks/CU by LDS. Q dead by the time Os overwrites it.
//  * Q pitch 72 shorts: bank = (4*(row+quad)+j)%32, uniform over 32 banks ->
//    conflict-free ds_read_b128. (Linear pitch 64 would be 16-way.)
//  * QK loop restructured tq-outer/tk-inner: 8 Q ds_read_b128/iter, 2 live regs.
//    Pl writes alias PO -> compiler cannot LICM-hoist Q reads back into registers.
//  * kf reload moved after the QK phase (PV hides it); vf reload after PV (next
//    QK hides it). Same single-buffer discipline as R2.
#define PPAD 40   // P^T row pitch (shorts)
#define OPAD 72   // O^T stash row pitch (shorts)
#define QPITCH 72 // Q tile row pitch (shorts) — uniform bank spread
__global__ __launch_bounds__(256, 2) void k_attn(
    const unsigned short* __restrict__ qkv, // bf16 (Q pre-scaled by 0.125*log2e)
    const unsigned short* __restrict__ vtg, // f16 V^T [bh][d][s]
    float* __restrict__ out)
{
    __shared__ __align__(16) unsigned short PO[4*64*OPAD];  // 36 KB union: Pl+Q (loop) / Os (epilogue)
    __shared__ float Lp[4*64];

    const int t = threadIdx.x;
    const int wave = t >> 6, lane = t & 63, quad = lane >> 4, l15 = lane & 15;
    const int bh = blockIdx.x, b = bh >> 4, h = bh & 15;
    const int m0 = blockIdx.y * 64;
    const unsigned short* base  = qkv + (size_t)(b*SEQ)*NQKV + h*(3*DH);
    const unsigned short* kbase = base + DH;
    const unsigned short* vbase = vtg + (size_t)bh * DH * SEQ;

    unsigned short* Qs = &PO[4*64*PPAD];   // [10240 .. 10240+64*72) shorts, inside PO tail

    // cooperative Q stage: 64 rows x 64 cols bf16 -> LDS pitch QPITCH
    {
        #pragma unroll
        for (int i = 0; i < 2; ++i) {
            int idx = t + i*256;
            int r = idx >> 3, cg = idx & 7;
            uint4 v = *(const uint4*)(base + (size_t)(m0 + r)*NQKV + cg*8);
            *(uint4*)(&Qs[r*QPITCH + cg*8]) = v;
        }
    }

    f32x4 o[4][4] = {};            // O^T tiles [td][tq]: row=d, col=q
    float lp[4] = {0.f, 0.f, 0.f, 0.f};
    unsigned short* pw = &PO[wave*64*PPAD];

    // single-buffered K/V fragments (direct global loads, L2-resident on this XCD)
    bf16x8 kf[2][2];   // [tk][kc]
    f16x8  vf[4];      // [td]
    {
        int key0 = wave*32;
        #pragma unroll
        for (int tk = 0; tk < 2; ++tk) {
            const unsigned short* kr = kbase + (size_t)(key0 + tk*16 + l15)*NQKV;
            kf[tk][0] = *(const bf16x8*)(kr + quad*8);
            kf[tk][1] = *(const bf16x8*)(kr + 32 + quad*8);
        }
        #pragma unroll
        for (int td = 0; td < 4; ++td)
            vf[td] = *(const f16x8*)(vbase + (size_t)(td*16 + l15)*SEQ + key0 + quad*8);
    }
    __syncthreads();   // Q staged before first QK read

    for (int it = 0; it < 16; ++it) {
        // S^T tiles: C'[key][q]: row=key_local=tk*16+quad*4+r, col=q=tq*16+l15
        #pragma unroll
        for (int tq = 0; tq < 4; ++tq) {
            bf16x8 q0 = *(const bf16x8*)(&Qs[(tq*16 + l15)*QPITCH + quad*8]);
            bf16x8 q1 = *(const bf16x8*)(&Qs[(tq*16 + l15)*QPITCH + 32 + quad*8]);
            #pragma unroll
            for (int tk = 0; tk < 2; ++tk) {
                f32x4 a = {};
                __builtin_amdgcn_s_setprio(1);
                a = __builtin_amdgcn_mfma_f32_16x16x32_bf16(kf[tk][0], q0, a, 0, 0, 0);
                a = __builtin_amdgcn_mfma_f32_16x16x32_bf16(kf[tk][1], q1, a, 0, 0, 0);
                __builtin_amdgcn_s_setprio(0);
                float p0 = exp2f(a[0]), p1 = exp2f(a[1]);   // scale pre-folded into Q
                float p2 = exp2f(a[2]), p3 = exp2f(a[3]);
                lp[tq] += (p0 + p1) + (p2 + p3);
                uint2 u; u.x = pkh(p0, p1); u.y = pkh(p2, p3);
                *(uint2*)(&pw[(tq*16 + l15)*PPAD + tk*16 + quad*4]) = u;
            }
        }
        // kf fully consumed -> reload same regs; PV phase hides the latency
        if (it < 15) {
            int key0 = (it+1)*128 + wave*32;
            #pragma unroll
            for (int tk = 0; tk < 2; ++tk) {
                const unsigned short* kr = kbase + (size_t)(key0 + tk*16 + l15)*NQKV;
                kf[tk][0] = *(const bf16x8*)(kr + quad*8);
                kf[tk][1] = *(const bf16x8*)(kr + 32 + quad*8);
            }
        }
        // O^T += V^T · P^T  (A=V^T m=d; B=P^T n=q, k=key=quad*8+j)
        #pragma unroll
        for (int tq = 0; tq < 4; ++tq) {
            f16x8 pb = *(const f16x8*)(&pw[(tq*16 + l15)*PPAD + quad*8]);
            __builtin_amdgcn_s_setprio(1);
            #pragma unroll
            for (int td = 0; td < 4; ++td)
                o[td][tq] = __builtin_amdgcn_mfma_f32_16x16x32_f16(vf[td], pb, o[td][tq], 0, 0, 0);
            __builtin_amdgcn_s_setprio(0);
        }
        // vf fully consumed -> reload same regs; next QK phase hides the latency
        if (it < 15) {
            int key0 = (it+1)*128 + wave*32;
            #pragma unroll
            for (int td = 0; td < 4; ++td)
                vf[td] = *(const f16x8*)(vbase + (size_t)(td*16 + l15)*SEQ + key0 + quad*8);
        }
    }

    // l partials (Lp is a separate region — safe before the union barrier)
    #pragma unroll
    for (int tq = 0; tq < 4; ++tq) {
        float s = lp[tq];
        s += __shfl_xor(s, 16);
        s += __shfl_xor(s, 32);
        if (quad == 0) Lp[wave*64 + tq*16 + l15] = s;
    }
    __syncthreads();   // all waves done reading Pl+Q before Os overwrites
    {
        unsigned short* ow = &PO[wave*64*OPAD];
        #pragma unroll
        for (int td = 0; td < 4; ++td)
            #pragma unroll
            for (int tq = 0; tq < 4; ++tq) {
                uint2 u; u.x = pkh(o[td][tq][0], o[td][tq][1]); u.y = pkh(o[td][tq][2], o[td][tq][3]);
                *(uint2*)(&ow[(tq*16 + l15)*OPAD + td*16 + quad*4]) = u;
            }
    }
    __syncthreads();
    float* outb = out + (size_t)(b*SEQ + m0) * (NHEADS*DH) + h*DH;
    #pragma unroll
    for (int i = 0; i < 16; ++i) {
        int idx = t + i*256;
        int q = idx >> 6, d = idx & 63;
        float lt = Lp[q] + Lp[64 + q] + Lp[128 + q] + Lp[192 + q];
        float s = 0.f;
        #pragma unroll
        for (int w2 = 0; w2 < 4; ++w2) {
            _Float16 hv = *(const _Float16*)&PO[(w2*64 + q)*OPAD + d];
            s += (float)hv;
        }
        outb[(size_t)q * (NHEADS*DH) + d] = s / lt;
    }
}

extern "C" void kernel_launch(void* const* d_in, const int* in_sizes, int n_in,
                              void* d_out, int out_size, void* d_ws, size_t ws_size,
                              hipStream_t stream) {
    const float* x    = (const float*)d_in[0];
    const float* W    = (const float*)d_in[1];
    const float* bias = (const float*)d_in[2];
    float* out = (float*)d_out;

    unsigned short* xb  = (unsigned short*)d_ws;                 // 16 MB (reused as vtg after GEMM)
    unsigned short* Wt  = xb  + (size_t)MTOT * D_IN;             // 6 MB
    unsigned short* qkv = Wt  + (size_t)NQKV * D_IN;             // 48 MB
    unsigned short* vtg = xb;                                    // alias: xb dead after GEMM

    hipLaunchKernelGGL(k_convert_x,   dim3(MTOT*D_IN/4/256), dim3(256),    0, stream, x, xb);
    hipLaunchKernelGGL(k_convert_wt,  dim3(NQKV/32, D_IN/32), dim3(32, 8), 0, stream, W, Wt);
    hipLaunchKernelGGL(k_gemm_qkv,    dim3(NQKV/128, MTOT/128), dim3(256), 0, stream, xb, Wt, bias, qkv);
    hipLaunchKernelGGL(k_transpose_v, dim3(BATCH*NHEADS, SEQ/64), dim3(256), 0, stream, qkv, vtg);
    hipLaunchKernelGGL(k_attn,        dim3(BATCH*NHEADS, SEQ/64), dim3(256), 0, stream, qkv, vtg, out);
}